// Round 9
// baseline (1802.438 us; speedup 1.0000x reference)
//
#include <hip/hip_runtime.h>
#include <hip/hip_bf16.h>
#include <cstdint>
#include <cstddef>

// B=16, S=128, IN=200, H=256, 4H=1024, 2H=512

typedef __attribute__((ext_vector_type(8))) short bf16x8;
typedef __attribute__((ext_vector_type(4))) float f32x4;
typedef __attribute__((ext_vector_type(4))) unsigned short u16x4;

__device__ __forceinline__ float bf2f(unsigned short u) {
    return __uint_as_float(((unsigned)u) << 16);
}
__device__ __forceinline__ unsigned short f2bf(float f) {
    unsigned u = __float_as_uint(f);
    u = (u + 0x7FFFu + ((u >> 16) & 1u)) >> 16;
    return (unsigned short)u;
}

// ---------------- prep kernels ----------------

// dst[z][k][n] = src[z][n][k], n<1024, k<K
__global__ void k_transpose_N1024(const float* __restrict__ src, float* __restrict__ dst, int K) {
    int z = blockIdx.z;
    int idx = blockIdx.x * 256 + threadIdx.x;
    if (idx >= K * 1024) return;
    int k = idx >> 10, n = idx & 1023;
    dst[(size_t)z * K * 1024 + idx] = src[(size_t)z * 1024 * K + (size_t)n * K + k];
}

// Whh (2,1024,256) fp32 -> A-fragment layout bf16
__global__ void k_wfrag(const float* __restrict__ Whh, unsigned short* __restrict__ Wfrag) {
    int idx = blockIdx.x * 256 + threadIdx.x;   // 65536 total
    int l = idx & 63;
    int t = (idx >> 6) & 3;
    int ks = (idx >> 8) & 7;
    int w = (idx >> 11) & 15;
    int d = idx >> 15;
    int r = l & 15;
    int kbase = ks * 32 + (l >> 4) * 8;
    int row = (r & 3) * 256 + w * 16 + t * 4 + (r >> 2);
    const float* src = Whh + (size_t)d * (1024 * 256) + (size_t)row * 256 + kbase;
    unsigned short* dst = Wfrag + (size_t)idx * 8;
#pragma unroll
    for (int e = 0; e < 8; ++e) dst[e] = f2bf(src[e]);
}

// W2 (128,256) fp32 -> B-fragment layout bf16
__global__ void k_w2frag(const float* __restrict__ W2, unsigned short* __restrict__ w2f) {
    int idx = blockIdx.x * 256 + threadIdx.x;   // 4096 total
    if (idx >= 4096) return;
    int l = idx & 63;
    int ks = (idx >> 6) & 7;
    int nt = idx >> 9;
    const float* src = W2 + (size_t)(nt * 16 + (l & 15)) * 256 + ks * 32 + (l >> 4) * 8;
    unsigned short* dst = w2f + (size_t)idx * 8;
#pragma unroll
    for (int e = 0; e < 8; ++e) dst[e] = f2bf(src[e]);
}

// W1 (256,1024) -> dst[k][o], k<512, o<512
__global__ void k_w1t(const float* __restrict__ W1, float* __restrict__ dst) {
    int idx = blockIdx.x * 256 + threadIdx.x;
    if (idx >= 512 * 512) return;
    int k = idx >> 9, o = idx & 511;
    dst[idx] = (o < 256) ? W1[(size_t)o * 1024 + k] : W1[(size_t)(o - 256) * 1024 + 512 + k];
}

__global__ void k_bias(const float* __restrict__ bih0, const float* __restrict__ bhh0,
                       const float* __restrict__ bih1, const float* __restrict__ bhh1,
                       const float* __restrict__ b1,
                       float* __restrict__ bsum0, float* __restrict__ bsum1, float* __restrict__ bhab) {
    int idx = blockIdx.x * 256 + threadIdx.x;
    if (idx < 2048) bsum0[idx] = bih0[idx] + bhh0[idx];
    else if (idx < 4096) { int i = idx - 2048; bsum1[i] = bih1[i] + bhh1[i]; }
    else if (idx < 4608) { int i = idx - 4096; bhab[i] = (i < 256) ? b1[i] : 0.f; }
}

// xg[d][b*128+t][n] -> xgfrag
__global__ __launch_bounds__(256) void k_reorder(const float* __restrict__ xg, float* __restrict__ xgf) {
    int idx = blockIdx.x * 256 + threadIdx.x;   // 1048576 total
    int n4 = idx & 255;
    int m = (idx >> 8) & 2047;
    int d = idx >> 19;
    int n0 = n4 * 4;
    int q = n0 >> 8;
    int jbase = n0 & 255;
    int b = m >> 7, t = m & 127;
    float4 v = *(const float4*)(xg + ((size_t)(d * 2048 + m)) * 1024 + n0);
    float* base = xgf + (size_t)d * 2097152;
    float vv[4] = {v.x, v.y, v.z, v.w};
#pragma unroll
    for (int dj = 0; dj < 4; ++dj) {
        int j = jbase + dj;
        int fi = (t * 4096 + (j >> 4) * 256 + ((j >> 2) & 3) * 64 + dj * 16 + b) * 4 + q;
        base[fi] = vv[dj];
    }
}

// ---------------- generic GEMM ----------------
__global__ __launch_bounds__(256) void k_gemm(
    const float* __restrict__ A, const float* __restrict__ Wt,
    const float* __restrict__ bias, float* __restrict__ out,
    int M, int K, int N)
{
    int z = blockIdx.z;
    const float* Wtz = Wt + (size_t)z * K * N;
    float* outz = out + (size_t)z * M * N;
    const float* biasz = bias + (size_t)z * N;

    __shared__ float As[16 * 512];
    int tid = threadIdx.x;
    int mq = tid >> 6;
    int nq = tid & 63;
    int n0 = blockIdx.x * 256 + nq * 4;
    int mbase = blockIdx.y * 16;

    for (int r = 0; r < 16; ++r) {
        const float* Ar = A + (size_t)(mbase + r) * K;
        for (int c = tid; c < K; c += 256) As[r * K + c] = Ar[c];
    }
    __syncthreads();

    float4 bv = *(const float4*)(biasz + n0);
    float acc[4][4];
#pragma unroll
    for (int mi = 0; mi < 4; mi++) { acc[mi][0] = bv.x; acc[mi][1] = bv.y; acc[mi][2] = bv.z; acc[mi][3] = bv.w; }

    const float* asr = As + (mq * 4) * K;
    for (int k = 0; k < K; ++k) {
        float4 w = *(const float4*)(Wtz + (size_t)k * N + n0);
        float x0 = asr[k];
        float x1 = asr[K + k];
        float x2 = asr[2 * K + k];
        float x3 = asr[3 * K + k];
        acc[0][0] += x0 * w.x; acc[0][1] += x0 * w.y; acc[0][2] += x0 * w.z; acc[0][3] += x0 * w.w;
        acc[1][0] += x1 * w.x; acc[1][1] += x1 * w.y; acc[1][2] += x1 * w.z; acc[1][3] += x1 * w.w;
        acc[2][0] += x2 * w.x; acc[2][1] += x2 * w.y; acc[2][2] += x2 * w.z; acc[2][3] += x2 * w.w;
        acc[3][0] += x3 * w.x; acc[3][1] += x3 * w.y; acc[3][2] += x3 * w.z; acc[3][3] += x3 * w.w;
    }
#pragma unroll
    for (int mi = 0; mi < 4; mi++) {
        size_t m = (size_t)mbase + mq * 4 + mi;
        *(float4*)(outz + m * N + n0) = make_float4(acc[mi][0], acc[mi][1], acc[mi][2], acc[mi][3]);
    }
}

// Same GEMM but A is bf16 in [t][j][b] layout
__global__ __launch_bounds__(256) void k_gemm_tl(
    const unsigned short* __restrict__ embt, const float* __restrict__ Wt,
    const float* __restrict__ bias, float* __restrict__ out,
    int K, int N)
{
    int z = blockIdx.z;
    const float* Wtz = Wt + (size_t)z * K * N;
    float* outz = out + (size_t)z * 2048 * N;
    const float* biasz = bias + (size_t)z * N;

    __shared__ float As[16 * 512];
    int tid = threadIdx.x;
    int mq = tid >> 6;
    int nq = tid & 63;
    int n0 = blockIdx.x * 256 + nq * 4;
    int mbase = blockIdx.y * 16;
    int bb = mbase >> 7;
    int tt0 = mbase & 127;

    for (int r = 0; r < 16; ++r) {
        const unsigned short* Ar = embt + (size_t)(tt0 + r) * 8192 + bb;
        for (int c = tid; c < K; c += 256) As[r * K + c] = bf2f(Ar[c * 16]);
    }
    __syncthreads();

    float4 bv = *(const float4*)(biasz + n0);
    float acc[4][4];
#pragma unroll
    for (int mi = 0; mi < 4; mi++) { acc[mi][0] = bv.x; acc[mi][1] = bv.y; acc[mi][2] = bv.z; acc[mi][3] = bv.w; }

    const float* asr = As + (mq * 4) * K;
    for (int k = 0; k < K; ++k) {
        float4 w = *(const float4*)(Wtz + (size_t)k * N + n0);
        float x0 = asr[k];
        float x1 = asr[K + k];
        float x2 = asr[2 * K + k];
        float x3 = asr[3 * K + k];
        acc[0][0] += x0 * w.x; acc[0][1] += x0 * w.y; acc[0][2] += x0 * w.z; acc[0][3] += x0 * w.w;
        acc[1][0] += x1 * w.x; acc[1][1] += x1 * w.y; acc[1][2] += x1 * w.z; acc[1][3] += x1 * w.w;
        acc[2][0] += x2 * w.x; acc[2][1] += x2 * w.y; acc[2][2] += x2 * w.z; acc[2][3] += x2 * w.w;
        acc[3][0] += x3 * w.x; acc[3][1] += x3 * w.y; acc[3][2] += x3 * w.z; acc[3][3] += x3 * w.w;
    }
#pragma unroll
    for (int mi = 0; mi < 4; mi++) {
        size_t m = (size_t)mbase + mq * 4 + mi;
        *(float4*)(outz + m * N + n0) = make_float4(acc[mi][0], acc[mi][1], acc[mi][2], acc[mi][3]);
    }
}

// ---------------- MFMA LSTM recurrence: one block per direction ----------------
// R7 structure (single hB, 2 barriers, late prefetch-into-acc, [t][j][b] emb store)
// + ALL 8 weight k-slices pinned in VGPRs via asm-opacity (no remat/reload).
#define GATE(A, C, H) { \
    float gi = A[0], gf = A[1], gg = A[2], go = A[3]; \
    float si = __builtin_amdgcn_rcpf(1.f + __expf(-gi)); \
    float sf = __builtin_amdgcn_rcpf(1.f + __expf(-gf)); \
    float so = __builtin_amdgcn_rcpf(1.f + __expf(-go)); \
    float eg = __expf(2.f * gg); \
    float tg = 1.f - 2.f * __builtin_amdgcn_rcpf(eg + 1.f); \
    C = sf * C + si * tg; \
    float ec = __expf(2.f * C); \
    float tc = 1.f - 2.f * __builtin_amdgcn_rcpf(ec + 1.f); \
    H = so * tc; }

__global__ __launch_bounds__(1024) void k_lstm_mfma(
    const float* __restrict__ xgf,            // [2][128][16][4][64][4]
    const unsigned short* __restrict__ Wfrag, // [2][16][8][4][64][8] bf16
    unsigned short* __restrict__ embt)        // [128][512][16] bf16 ([t][j][b])
{
    const int d = blockIdx.x;
    const int tid = threadIdx.x;
    const int w = tid >> 6;
    const int l = tid & 63;
    const int b = l & 15;
    const int jh = l >> 4;

    __shared__ __align__(16) unsigned short hB[4096];   // 8 KiB, single buffer

    // load ALL 8 weight k-slices, then PIN them in VGPRs: the empty asm makes
    // each value opaque so the compiler cannot rematerialize (re-load) it
    // inside the loop. This is the fix for the VGPR_Count=64 reload pathology.
    const unsigned short* wgp = Wfrag + ((size_t)(d * 16 + w)) * (8 * 4 * 64 * 8);
    bf16x8 Wr[8][4];
#pragma unroll
    for (int ks = 0; ks < 8; ++ks)
#pragma unroll
        for (int t4 = 0; t4 < 4; ++t4)
            Wr[ks][t4] = *(const bf16x8*)(wgp + ((ks * 4 + t4) * 64 + l) * 8);
#pragma unroll
    for (int ks = 0; ks < 8; ++ks)
#pragma unroll
        for (int t4 = 0; t4 < 4; ++t4)
            asm volatile("" : "+v"(Wr[ks][t4]));

    // zero h state
    *(uint2*)(&hB[tid * 4]) = make_uint2(0u, 0u);

    const int sgn = d ? -1 : 1;
    int t = d ? 127 : 0;
    const f32x4* xb = (const f32x4*)(xgf) + (size_t)d * 524288;
    const int xo = w * 256 + l;

    f32x4 a0 = xb[t * 4096 + xo];
    f32x4 a1 = xb[t * 4096 + xo + 64];
    f32x4 a2 = xb[t * 4096 + xo + 128];
    f32x4 a3 = xb[t * 4096 + xo + 192];

    float c0 = 0.f, c1 = 0.f, c2 = 0.f, c3 = 0.f;
    const int hoff = jh * 128 + b * 8;     // + ks*512 (u16)
    const int hwoff = w * 256 + b * 8 + jh;
    unsigned short* embp = embt + (size_t)d * 4096 + (size_t)w * 256 + l;
    __syncthreads();

    for (int s = 0; s < 128; ++s) {
#pragma unroll
        for (int ks = 0; ks < 8; ++ks) {
            bf16x8 hf = *(const bf16x8*)(&hB[ks * 512 + hoff]);
            a0 = __builtin_amdgcn_mfma_f32_16x16x32_bf16(Wr[ks][0], hf, a0, 0, 0, 0);
            a1 = __builtin_amdgcn_mfma_f32_16x16x32_bf16(Wr[ks][1], hf, a1, 0, 0, 0);
            a2 = __builtin_amdgcn_mfma_f32_16x16x32_bf16(Wr[ks][2], hf, a2, 0, 0, 0);
            a3 = __builtin_amdgcn_mfma_f32_16x16x32_bf16(Wr[ks][3], hf, a3, 0, 0, 0);
        }

        // gate nonlinearity (acc includes xg + biases via C-init)
        float h0, h1, h2, h3;
        GATE(a0, c0, h0);
        GATE(a1, c1, h1);
        GATE(a2, c2, h2);
        GATE(a3, c3, h3);
        unsigned short u0 = f2bf(h0), u1 = f2bf(h1), u2 = f2bf(h2), u3 = f2bf(h3);

        // emb global write: [t][j][b] layout -> 4 fully-coalesced 128B wave stores
        {
            unsigned short* ep = embp + (size_t)t * 8192;
            ep[0]   = u0;
            ep[64]  = u1;
            ep[128] = u2;
            ep[192] = u3;
        }
        // prefetch next step's xg into acc (drained by the barrier)
        int tn = (s == 127) ? t : (t + sgn);
        a0 = xb[tn * 4096 + xo];
        a1 = xb[tn * 4096 + xo + 64];
        a2 = xb[tn * 4096 + xo + 128];
        a3 = xb[tn * 4096 + xo + 192];
        __syncthreads();   // all reads of h_{s-1} complete
        hB[hwoff] = u0;
        hB[hwoff + 4] = u1;
        hB[hwoff + 128] = u2;
        hB[hwoff + 132] = u3;
        __syncthreads();   // h_s visible
        t = tn;
    }
}

// ---------------- MFMA pairwise scorer (R7 winner, unchanged) ----------------
__global__ __launch_bounds__(256, 2) void k_scorer_mfma(
    const float* __restrict__ HaHb, const unsigned short* __restrict__ w2f,
    const float* __restrict__ b2, const float* __restrict__ W3,
    const float* __restrict__ b3v, float* __restrict__ score)
{
    const int jt = blockIdx.x, it = blockIdx.y, b = blockIdx.z;
    const int j0 = jt * 16, i0 = it * 16;
    const int tid = threadIdx.x;
    const int w = tid >> 6;
    const int l = tid & 63;
    const int n_l = l & 15;
    const int kq = l >> 4;

    __shared__ __align__(16) unsigned short HaS[16 * 264];
    __shared__ __align__(16) unsigned short HbS[16 * 264];

    {
        const float* base = HaHb + ((size_t)(b * 128)) * 512;
        int rr = tid >> 4;
        int q = tid & 15;
#pragma unroll
        for (int rep = 0; rep < 4; ++rep) {
            int k0 = q * 4 + rep * 64;
            float4 va = *(const float4*)(base + (size_t)(i0 + rr) * 512 + k0);
            float4 vb = *(const float4*)(base + (size_t)(j0 + rr) * 512 + 256 + k0);
            u16x4 ua = { f2bf(va.x), f2bf(va.y), f2bf(va.z), f2bf(va.w) };
            u16x4 ub = { f2bf(vb.x), f2bf(vb.y), f2bf(vb.z), f2bf(vb.w) };
            *(u16x4*)(&HaS[rr * 264 + k0]) = ua;
            *(u16x4*)(&HbS[rr * 264 + k0]) = ub;
        }
    }

    float b2v[8], w3v[8];
#pragma unroll
    for (int nt = 0; nt < 8; ++nt) {
        b2v[nt] = b2[nt * 16 + n_l];
        w3v[nt] = W3[nt * 16 + n_l];
    }

    f32x4 acc[4][8];
#pragma unroll
    for (int il = 0; il < 4; ++il)
#pragma unroll
        for (int nt = 0; nt < 8; ++nt) acc[il][nt] = f32x4{0.f, 0.f, 0.f, 0.f};

    const bf16x8* wbase = (const bf16x8*)w2f;
    bf16x8 wf[8], wfn[8];
#pragma unroll
    for (int nt = 0; nt < 8; ++nt) wf[nt] = wbase[(nt * 8 + 0) * 64 + l];

    __syncthreads();

#pragma unroll
    for (int ks = 0; ks < 8; ++ks) {
        if (ks < 7) {
#pragma unroll
            for (int nt = 0; nt < 8; ++nt) wfn[nt] = wbase[(nt * 8 + ks + 1) * 64 + l];
        }
#pragma unroll
        for (int il = 0; il < 4; ++il) {
            const int irow = w * 4 + il;
            bf16x8 ha = *(const bf16x8*)(&HaS[irow * 264 + ks * 32 + kq * 8]);
            bf16x8 hb = *(const bf16x8*)(&HbS[n_l * 264 + ks * 32 + kq * 8]);
            bf16x8 av;
#pragma unroll
            for (int e = 0; e < 8; ++e) {
                float v = bf2f((unsigned short)ha[e]) + bf2f((unsigned short)hb[e]);
                v = v > 0.f ? v : 0.f;
                av[e] = (short)f2bf(v);
            }
#pragma unroll
            for (int nt = 0; nt < 8; ++nt)
                acc[il][nt] = __builtin_amdgcn_mfma_f32_16x16x32_bf16(av, wf[nt], acc[il][nt], 0, 0, 0);
        }
#pragma unroll
        for (int nt = 0; nt < 8; ++nt) wf[nt] = wfn[nt];
    }

    const float bb3 = b3v[0];
#pragma unroll
    for (int il = 0; il < 4; ++il) {
        float p[4];
#pragma unroll
        for (int reg = 0; reg < 4; ++reg) {
            float v = 0.f;
#pragma unroll
            for (int nt = 0; nt < 8; ++nt) {
                float h2v = acc[il][nt][reg] + b2v[nt];
                h2v = h2v > 0.f ? h2v : 0.f;
                v += h2v * w3v[nt];
            }
            p[reg] = v;
        }
#pragma unroll
        for (int m = 1; m < 16; m <<= 1) {
            p[0] += __shfl_xor(p[0], m);
            p[1] += __shfl_xor(p[1], m);
            p[2] += __shfl_xor(p[2], m);
            p[3] += __shfl_xor(p[3], m);
        }
        if (n_l == 0) {
            const int i = i0 + w * 4 + il;
            const int jb = j0 + kq * 4;
            float4 sv;
            float* pv = &sv.x;
#pragma unroll
            for (int reg = 0; reg < 4; ++reg) {
                int jg = jb + reg;
                float sc = p[reg] + bb3;
                sc = sc > 0.f ? sc : 0.f;
                if (jg == i || jg == 0) sc = 0.f;
                pv[reg] = sc;
            }
            *(float4*)(&score[((size_t)(b * 128 + i)) * 128 + jb]) = sv;
        }
    }
}

// ---------------- loss ----------------
__global__ __launch_bounds__(128) void k_loss1(
    const float* __restrict__ score, const int* __restrict__ tree, float* __restrict__ res)
{
    int k = blockIdx.x;
    int b = blockIdx.y;
    int head = tree[((size_t)b * 128 + k + 1) * 2 + 0];
    int dep  = tree[((size_t)b * 128 + k + 1) * 2 + 1];
    int i = threadIdx.x;
    float s = score[((size_t)b * 128 + i) * 128 + dep];
    float v = (i == dep) ? 0.f : __expf(s);
    __shared__ float redu[2];
#pragma unroll
    for (int off = 32; off >= 1; off >>= 1) v += __shfl_down(v, off, 64);
    if ((i & 63) == 0) redu[i >> 6] = v;
    __syncthreads();
    if (i == 0) {
        float norm = redu[0] + redu[1];
        float num = score[((size_t)b * 128 + head) * 128 + dep];
        res[b * 127 + k] = __logf(norm) - num;
    }
}

__global__ __launch_bounds__(256) void k_loss2(const float* __restrict__ res, float* __restrict__ out) {
    int tid = threadIdx.x;
    float a = 0.f;
    for (int idx = tid; idx < 16 * 127; idx += 256) a += res[idx];
    __shared__ float sm[256];
    sm[tid] = a;
    __syncthreads();
    for (int off = 128; off >= 1; off >>= 1) {
        if (tid < off) sm[tid] += sm[tid + off];
        __syncthreads();
    }
    if (tid == 0) out[0] = sm[0] / 127.f;
}

// ---------------- host launcher ----------------
extern "C" void kernel_launch(void* const* d_in, const int* in_sizes, int n_in,
                              void* d_out, int out_size, void* d_ws, size_t ws_size,
                              hipStream_t stream) {
    (void)in_sizes; (void)n_in; (void)out_size; (void)ws_size;
    const float* X    = (const float*)d_in[0];
    const float* Wih0 = (const float*)d_in[1];
    const float* Whh0 = (const float*)d_in[2];
    const float* bih0 = (const float*)d_in[3];
    const float* bhh0 = (const float*)d_in[4];
    const float* Wih1 = (const float*)d_in[5];
    const float* Whh1 = (const float*)d_in[6];
    const float* bih1 = (const float*)d_in[7];
    const float* bhh1 = (const float*)d_in[8];
    const float* W1   = (const float*)d_in[9];
    const float* b1   = (const float*)d_in[10];
    const float* W2   = (const float*)d_in[11];
    const float* b2   = (const float*)d_in[12];
    const float* W3   = (const float*)d_in[13];
    const float* b3   = (const float*)d_in[14];
    const int*   tree = (const int*)d_in[15];
    float* out = (float*)d_out;   // [0]=loss, [1..]=score

    float* ws = (float*)d_ws;
    size_t o = 0;
    float* WihT0 = ws + o; o += (size_t)2 * 200 * 1024;
    float* WihT1 = ws + o; o += (size_t)2 * 512 * 1024;
    float* W1T   = ws + o; o += (size_t)512 * 512;
    float* bsum0 = ws + o; o += 2048;
    float* bsum1 = ws + o; o += 2048;
    float* bhab  = ws + o; o += 512;
    unsigned short* Wf0 = (unsigned short*)(ws + o); o += (size_t)2 * 16 * 8 * 4 * 64 * 8 / 2;
    unsigned short* Wf1 = (unsigned short*)(ws + o); o += (size_t)2 * 16 * 8 * 4 * 64 * 8 / 2;
    unsigned short* w2f = (unsigned short*)(ws + o); o += (size_t)8 * 8 * 64 * 8 / 2;
    float* xg   = ws + o; o += (size_t)2 * 2048 * 1024;
    float* xgf  = ws + o; o += (size_t)2 * 2048 * 1024;
    unsigned short* embt0 = (unsigned short*)(ws + o); o += (size_t)128 * 512 * 16 / 2;
    unsigned short* embt1 = (unsigned short*)(ws + o); o += (size_t)128 * 512 * 16 / 2;
    float* HaHb = ws + o; o += (size_t)2048 * 512;
    float* res  = ws + o; o += 2048;

    // prep
    k_transpose_N1024<<<dim3(800, 1, 2), 256, 0, stream>>>(Wih0, WihT0, 200);
    k_transpose_N1024<<<dim3(2048, 1, 2), 256, 0, stream>>>(Wih1, WihT1, 512);
    k_wfrag<<<256, 256, 0, stream>>>(Whh0, Wf0);
    k_wfrag<<<256, 256, 0, stream>>>(Whh1, Wf1);
    k_w2frag<<<16, 256, 0, stream>>>(W2, w2f);
    k_w1t<<<1024, 256, 0, stream>>>(W1, W1T);
    k_bias<<<18, 256, 0, stream>>>(bih0, bhh0, bih1, bhh1, b1, bsum0, bsum1, bhab);

    // layer 0
    k_gemm<<<dim3(4, 128, 2), 256, 0, stream>>>(X, WihT0, bsum0, xg, 2048, 200, 1024);
    k_reorder<<<4096, 256, 0, stream>>>(xg, xgf);
    k_lstm_mfma<<<2, 1024, 0, stream>>>(xgf, Wf0, embt0);
    // layer 1
    k_gemm_tl<<<dim3(4, 128, 2), 256, 0, stream>>>(embt0, WihT1, bsum1, xg, 512, 1024);
    k_reorder<<<4096, 256, 0, stream>>>(xg, xgf);
    k_lstm_mfma<<<2, 1024, 0, stream>>>(xgf, Wf1, embt1);
    // Ha|Hb
    k_gemm_tl<<<dim3(2, 128, 1), 256, 0, stream>>>(embt1, W1T, bhab, HaHb, 512, 512);
    // scorer -> out+1
    k_scorer_mfma<<<dim3(8, 8, 16), 256, 0, stream>>>(HaHb, w2f, b2, W3, b3, out + 1);
    // loss
    k_loss1<<<dim3(127, 16), 128, 0, stream>>>(out + 1, tree, res);
    k_loss2<<<1, 256, 0, stream>>>(res, out);
}

// Round 10
// 1057.519 us; speedup vs baseline: 1.7044x; 1.7044x over previous
//
#include <hip/hip_runtime.h>
#include <hip/hip_bf16.h>
#include <cstdint>
#include <cstddef>

// B=16, S=128, IN=200, H=256, 4H=1024, 2H=512

typedef __attribute__((ext_vector_type(8))) short bf16x8;
typedef __attribute__((ext_vector_type(4))) float f32x4;
typedef __attribute__((ext_vector_type(4))) unsigned short u16x4;

__device__ __forceinline__ float bf2f(unsigned short u) {
    return __uint_as_float(((unsigned)u) << 16);
}
__device__ __forceinline__ unsigned short f2bf(float f) {
    unsigned u = __float_as_uint(f);
    u = (u + 0x7FFFu + ((u >> 16) & 1u)) >> 16;
    return (unsigned short)u;
}

// float -> OCP e4m3fn with RNE (software; saturating, no NaN emission)
__device__ __forceinline__ unsigned f2e4m3(float f) {
    unsigned u = __float_as_uint(f);
    unsigned s = (u >> 24) & 0x80u;
    int expf_ = (int)((u >> 23) & 0xFF);
    if (expf_ == 0) return s;                 // zero / f32-denormal -> 0
    int exp = expf_ - 127;
    if (exp < -10) return s;                  // below half of min subnormal
    unsigned M = (u & 0x7FFFFF) | 0x800000;   // 24-bit 1.m
    int e8 = exp + 7;
    int shift = 20;
    if (e8 < 1) { shift = 21 - e8; e8 = 0; }  // subnormal (unit 2^-9)
    unsigned q = M >> shift;
    unsigned rem = M & ((1u << shift) - 1u);
    unsigned half = 1u << (shift - 1);
    if (rem > half || (rem == half && (q & 1))) q++;
    if (q >= 16) { q >>= 1; e8++; }           // normal mantissa overflow
    if (e8 == 0 && (q & 8)) e8 = 1;           // subnormal rounded to min normal
    if (e8 >= 16 || (e8 == 15 && (q & 7) == 7)) return s | 0x7Eu;  // sat 448
    return s | ((unsigned)e8 << 4) | (q & 7u);
}

// ---------------- prep kernels ----------------

// dst[z][k][n] = src[z][n][k], n<1024, k<K
__global__ void k_transpose_N1024(const float* __restrict__ src, float* __restrict__ dst, int K) {
    int z = blockIdx.z;
    int idx = blockIdx.x * 256 + threadIdx.x;
    if (idx >= K * 1024) return;
    int k = idx >> 10, n = idx & 1023;
    dst[(size_t)z * K * 1024 + idx] = src[(size_t)z * 1024 * K + (size_t)n * K + k];
}

// Whh (2,1024,256) fp32 -> fp8(e4m3) A-fragment layout of 64*Whh:
// Wfrag8[(((d*16+w)*8+ks)*4+t)*64 + l][e] = e4m3(64*Whh[d][row][ks*32+(l>>4)*8+e])
// row = (r&3)*256 + w*16 + t*4 + (r>>2), r = l&15
__global__ void k_wfrag8(const float* __restrict__ Whh, unsigned char* __restrict__ Wfrag8) {
    int idx = blockIdx.x * 256 + threadIdx.x;   // 65536 total
    int l = idx & 63;
    int t = (idx >> 6) & 3;
    int ks = (idx >> 8) & 7;
    int w = (idx >> 11) & 15;
    int d = idx >> 15;
    int r = l & 15;
    int kbase = ks * 32 + (l >> 4) * 8;
    int row = (r & 3) * 256 + w * 16 + t * 4 + (r >> 2);
    const float* src = Whh + (size_t)d * (1024 * 256) + (size_t)row * 256 + kbase;
    unsigned char* dst = Wfrag8 + (size_t)idx * 8;
#pragma unroll
    for (int e = 0; e < 8; ++e) dst[e] = (unsigned char)f2e4m3(64.f * src[e]);
}

// W2 (128,256) fp32 -> B-fragment layout bf16
__global__ void k_w2frag(const float* __restrict__ W2, unsigned short* __restrict__ w2f) {
    int idx = blockIdx.x * 256 + threadIdx.x;   // 4096 total
    if (idx >= 4096) return;
    int l = idx & 63;
    int ks = (idx >> 6) & 7;
    int nt = idx >> 9;
    const float* src = W2 + (size_t)(nt * 16 + (l & 15)) * 256 + ks * 32 + (l >> 4) * 8;
    unsigned short* dst = w2f + (size_t)idx * 8;
#pragma unroll
    for (int e = 0; e < 8; ++e) dst[e] = f2bf(src[e]);
}

// W1 (256,1024) -> dst[k][o], k<512, o<512
__global__ void k_w1t(const float* __restrict__ W1, float* __restrict__ dst) {
    int idx = blockIdx.x * 256 + threadIdx.x;
    if (idx >= 512 * 512) return;
    int k = idx >> 9, o = idx & 511;
    dst[idx] = (o < 256) ? W1[(size_t)o * 1024 + k] : W1[(size_t)(o - 256) * 1024 + 512 + k];
}

__global__ void k_bias(const float* __restrict__ bih0, const float* __restrict__ bhh0,
                       const float* __restrict__ bih1, const float* __restrict__ bhh1,
                       const float* __restrict__ b1,
                       float* __restrict__ bsum0, float* __restrict__ bsum1, float* __restrict__ bhab) {
    int idx = blockIdx.x * 256 + threadIdx.x;
    if (idx < 2048) bsum0[idx] = bih0[idx] + bhh0[idx];
    else if (idx < 4096) { int i = idx - 2048; bsum1[i] = bih1[i] + bhh1[i]; }
    else if (idx < 4608) { int i = idx - 4096; bhab[i] = (i < 256) ? b1[i] : 0.f; }
}

// xg[d][b*128+t][n] -> xgfrag, PRE-SCALED by 64 (fp8 weight-scale compensation)
__global__ __launch_bounds__(256) void k_reorder(const float* __restrict__ xg, float* __restrict__ xgf) {
    int idx = blockIdx.x * 256 + threadIdx.x;   // 1048576 total
    int n4 = idx & 255;
    int m = (idx >> 8) & 2047;
    int d = idx >> 19;
    int n0 = n4 * 4;
    int q = n0 >> 8;
    int jbase = n0 & 255;
    int b = m >> 7, t = m & 127;
    float4 v = *(const float4*)(xg + ((size_t)(d * 2048 + m)) * 1024 + n0);
    float* base = xgf + (size_t)d * 2097152;
    float vv[4] = {v.x * 64.f, v.y * 64.f, v.z * 64.f, v.w * 64.f};
#pragma unroll
    for (int dj = 0; dj < 4; ++dj) {
        int j = jbase + dj;
        int fi = (t * 4096 + (j >> 4) * 256 + ((j >> 2) & 3) * 64 + dj * 16 + b) * 4 + q;
        base[fi] = vv[dj];
    }
}

// ---------------- generic GEMM ----------------
__global__ __launch_bounds__(256) void k_gemm(
    const float* __restrict__ A, const float* __restrict__ Wt,
    const float* __restrict__ bias, float* __restrict__ out,
    int M, int K, int N)
{
    int z = blockIdx.z;
    const float* Wtz = Wt + (size_t)z * K * N;
    float* outz = out + (size_t)z * M * N;
    const float* biasz = bias + (size_t)z * N;

    __shared__ float As[16 * 512];
    int tid = threadIdx.x;
    int mq = tid >> 6;
    int nq = tid & 63;
    int n0 = blockIdx.x * 256 + nq * 4;
    int mbase = blockIdx.y * 16;

    for (int r = 0; r < 16; ++r) {
        const float* Ar = A + (size_t)(mbase + r) * K;
        for (int c = tid; c < K; c += 256) As[r * K + c] = Ar[c];
    }
    __syncthreads();

    float4 bv = *(const float4*)(biasz + n0);
    float acc[4][4];
#pragma unroll
    for (int mi = 0; mi < 4; mi++) { acc[mi][0] = bv.x; acc[mi][1] = bv.y; acc[mi][2] = bv.z; acc[mi][3] = bv.w; }

    const float* asr = As + (mq * 4) * K;
    for (int k = 0; k < K; ++k) {
        float4 w = *(const float4*)(Wtz + (size_t)k * N + n0);
        float x0 = asr[k];
        float x1 = asr[K + k];
        float x2 = asr[2 * K + k];
        float x3 = asr[3 * K + k];
        acc[0][0] += x0 * w.x; acc[0][1] += x0 * w.y; acc[0][2] += x0 * w.z; acc[0][3] += x0 * w.w;
        acc[1][0] += x1 * w.x; acc[1][1] += x1 * w.y; acc[1][2] += x1 * w.z; acc[1][3] += x1 * w.w;
        acc[2][0] += x2 * w.x; acc[2][1] += x2 * w.y; acc[2][2] += x2 * w.z; acc[2][3] += x2 * w.w;
        acc[3][0] += x3 * w.x; acc[3][1] += x3 * w.y; acc[3][2] += x3 * w.z; acc[3][3] += x3 * w.w;
    }
#pragma unroll
    for (int mi = 0; mi < 4; mi++) {
        size_t m = (size_t)mbase + mq * 4 + mi;
        *(float4*)(outz + m * N + n0) = make_float4(acc[mi][0], acc[mi][1], acc[mi][2], acc[mi][3]);
    }
}

// Same GEMM but A is bf16 in [t][j][b] layout
__global__ __launch_bounds__(256) void k_gemm_tl(
    const unsigned short* __restrict__ embt, const float* __restrict__ Wt,
    const float* __restrict__ bias, float* __restrict__ out,
    int K, int N)
{
    int z = blockIdx.z;
    const float* Wtz = Wt + (size_t)z * K * N;
    float* outz = out + (size_t)z * 2048 * N;
    const float* biasz = bias + (size_t)z * N;

    __shared__ float As[16 * 512];
    int tid = threadIdx.x;
    int mq = tid >> 6;
    int nq = tid & 63;
    int n0 = blockIdx.x * 256 + nq * 4;
    int mbase = blockIdx.y * 16;
    int bb = mbase >> 7;
    int tt0 = mbase & 127;

    for (int r = 0; r < 16; ++r) {
        const unsigned short* Ar = embt + (size_t)(tt0 + r) * 8192 + bb;
        for (int c = tid; c < K; c += 256) As[r * K + c] = bf2f(Ar[c * 16]);
    }
    __syncthreads();

    float4 bv = *(const float4*)(biasz + n0);
    float acc[4][4];
#pragma unroll
    for (int mi = 0; mi < 4; mi++) { acc[mi][0] = bv.x; acc[mi][1] = bv.y; acc[mi][2] = bv.z; acc[mi][3] = bv.w; }

    const float* asr = As + (mq * 4) * K;
    for (int k = 0; k < K; ++k) {
        float4 w = *(const float4*)(Wtz + (size_t)k * N + n0);
        float x0 = asr[k];
        float x1 = asr[K + k];
        float x2 = asr[2 * K + k];
        float x3 = asr[3 * K + k];
        acc[0][0] += x0 * w.x; acc[0][1] += x0 * w.y; acc[0][2] += x0 * w.z; acc[0][3] += x0 * w.w;
        acc[1][0] += x1 * w.x; acc[1][1] += x1 * w.y; acc[1][2] += x1 * w.z; acc[1][3] += x1 * w.w;
        acc[2][0] += x2 * w.x; acc[2][1] += x2 * w.y; acc[2][2] += x2 * w.z; acc[2][3] += x2 * w.w;
        acc[3][0] += x3 * w.x; acc[3][1] += x3 * w.y; acc[3][2] += x3 * w.z; acc[3][3] += x3 * w.w;
    }
#pragma unroll
    for (int mi = 0; mi < 4; mi++) {
        size_t m = (size_t)mbase + mq * 4 + mi;
        *(float4*)(outz + m * N + n0) = make_float4(acc[mi][0], acc[mi][1], acc[mi][2], acc[mi][3]);
    }
}

// ---------------- MFMA LSTM recurrence (fp8 weights, register-resident) ----
// R7-proven step skeleton (single hB, 2 barriers, prefetch-into-acc before
// barrier, coalesced [t][j][b] emb store). Weights: 8 k-slices as fp8 = 64
// VGPRs -> fits the 128-reg budget at 1024 threads; pinned via asm opacity.
// acc = 64*(xg+bias) + (64*W)@h_fp8; GATE divides by 64.
#define GATE8(A, C, H) { \
    float gi = A[0] * 0.015625f, gf = A[1] * 0.015625f, gg = A[2] * 0.015625f, go = A[3] * 0.015625f; \
    float si = __builtin_amdgcn_rcpf(1.f + __expf(-gi)); \
    float sf = __builtin_amdgcn_rcpf(1.f + __expf(-gf)); \
    float so = __builtin_amdgcn_rcpf(1.f + __expf(-go)); \
    float eg = __expf(2.f * gg); \
    float tg = 1.f - 2.f * __builtin_amdgcn_rcpf(eg + 1.f); \
    C = sf * C + si * tg; \
    float ec = __expf(2.f * C); \
    float tc = 1.f - 2.f * __builtin_amdgcn_rcpf(ec + 1.f); \
    H = so * tc; }

__global__ __launch_bounds__(1024) void k_lstm_mfma(
    const float* __restrict__ xgf,            // [2][128][16][4][64][4], pre-scaled x64
    const unsigned char* __restrict__ Wfrag8, // [2][16][8][4][64][8] fp8 of 64*Whh
    unsigned short* __restrict__ embt)        // [128][512][16] bf16 ([t][j][b])
{
    const int d = blockIdx.x;
    const int tid = threadIdx.x;
    const int w = tid >> 6;
    const int l = tid & 63;
    const int b = l & 15;
    const int jh = l >> 4;

    __shared__ __align__(8) unsigned char hB[4096];   // 4 KiB fp8 h, single buffer

    // all 8 weight k-slices in VGPRs (fp8: 2 regs each = 64 total), pinned
    const unsigned char* wgp = Wfrag8 + ((size_t)(d * 16 + w)) * (8 * 4 * 64 * 8);
    long Wr[8][4];
#pragma unroll
    for (int ks = 0; ks < 8; ++ks)
#pragma unroll
        for (int t4 = 0; t4 < 4; ++t4)
            Wr[ks][t4] = *(const long*)(wgp + ((size_t)((ks * 4 + t4) * 64 + l)) * 8);
#pragma unroll
    for (int ks = 0; ks < 8; ++ks)
#pragma unroll
        for (int t4 = 0; t4 < 4; ++t4)
            asm volatile("" : "+v"(Wr[ks][t4]));

    // zero h state
    ((unsigned*)hB)[tid] = 0u;

    const int sgn = d ? -1 : 1;
    int t = d ? 127 : 0;
    const f32x4* xb = (const f32x4*)(xgf) + (size_t)d * 524288;
    const int xo = w * 256 + l;

    f32x4 a0 = xb[t * 4096 + xo];
    f32x4 a1 = xb[t * 4096 + xo + 64];
    f32x4 a2 = xb[t * 4096 + xo + 128];
    f32x4 a3 = xb[t * 4096 + xo + 192];

    float c0 = 0.f, c1 = 0.f, c2 = 0.f, c3 = 0.f;
    const int hrd = jh * 128 + b * 8;          // byte offset (+ ks*512)
    const int hwoff = w * 256 + b * 8 + jh;    // byte writes at +0,+4,+128,+132
    unsigned short* embp = embt + (size_t)d * 4096 + (size_t)w * 256 + l;
    __syncthreads();

    for (int s = 0; s < 128; ++s) {
#pragma unroll
        for (int ks = 0; ks < 8; ++ks) {
            long hf = *(const long*)(hB + ks * 512 + hrd);
            a0 = __builtin_amdgcn_mfma_f32_16x16x32_fp8_fp8(Wr[ks][0], hf, a0, 0, 0, 0);
            a1 = __builtin_amdgcn_mfma_f32_16x16x32_fp8_fp8(Wr[ks][1], hf, a1, 0, 0, 0);
            a2 = __builtin_amdgcn_mfma_f32_16x16x32_fp8_fp8(Wr[ks][2], hf, a2, 0, 0, 0);
            a3 = __builtin_amdgcn_mfma_f32_16x16x32_fp8_fp8(Wr[ks][3], hf, a3, 0, 0, 0);
        }

        float h0, h1, h2, h3;
        GATE8(a0, c0, h0);
        GATE8(a1, c1, h1);
        GATE8(a2, c2, h2);
        GATE8(a3, c3, h3);

        // emb global write (bf16, [t][j][b]): 4 fully-coalesced 128B wave stores
        {
            unsigned short* ep = embp + (size_t)t * 8192;
            ep[0]   = f2bf(h0);
            ep[64]  = f2bf(h1);
            ep[128] = f2bf(h2);
            ep[192] = f2bf(h3);
        }
        // fp8 h for the recurrence
        unsigned q0 = f2e4m3(h0), q1 = f2e4m3(h1), q2 = f2e4m3(h2), q3 = f2e4m3(h3);

        // prefetch next step's xg into acc (drained by the barrier)
        int tn = (s == 127) ? t : (t + sgn);
        a0 = xb[tn * 4096 + xo];
        a1 = xb[tn * 4096 + xo + 64];
        a2 = xb[tn * 4096 + xo + 128];
        a3 = xb[tn * 4096 + xo + 192];
        __syncthreads();   // all reads of h_{s-1} complete
        hB[hwoff]       = (unsigned char)q0;
        hB[hwoff + 4]   = (unsigned char)q1;
        hB[hwoff + 128] = (unsigned char)q2;
        hB[hwoff + 132] = (unsigned char)q3;
        __syncthreads();   // h_s visible
        t = tn;
    }
}

// ---------------- MFMA pairwise scorer (R7 winner, unchanged) ----------------
__global__ __launch_bounds__(256, 2) void k_scorer_mfma(
    const float* __restrict__ HaHb, const unsigned short* __restrict__ w2f,
    const float* __restrict__ b2, const float* __restrict__ W3,
    const float* __restrict__ b3v, float* __restrict__ score)
{
    const int jt = blockIdx.x, it = blockIdx.y, b = blockIdx.z;
    const int j0 = jt * 16, i0 = it * 16;
    const int tid = threadIdx.x;
    const int w = tid >> 6;
    const int l = tid & 63;
    const int n_l = l & 15;
    const int kq = l >> 4;

    __shared__ __align__(16) unsigned short HaS[16 * 264];
    __shared__ __align__(16) unsigned short HbS[16 * 264];

    {
        const float* base = HaHb + ((size_t)(b * 128)) * 512;
        int rr = tid >> 4;
        int q = tid & 15;
#pragma unroll
        for (int rep = 0; rep < 4; ++rep) {
            int k0 = q * 4 + rep * 64;
            float4 va = *(const float4*)(base + (size_t)(i0 + rr) * 512 + k0);
            float4 vb = *(const float4*)(base + (size_t)(j0 + rr) * 512 + 256 + k0);
            u16x4 ua = { f2bf(va.x), f2bf(va.y), f2bf(va.z), f2bf(va.w) };
            u16x4 ub = { f2bf(vb.x), f2bf(vb.y), f2bf(vb.z), f2bf(vb.w) };
            *(u16x4*)(&HaS[rr * 264 + k0]) = ua;
            *(u16x4*)(&HbS[rr * 264 + k0]) = ub;
        }
    }

    float b2v[8], w3v[8];
#pragma unroll
    for (int nt = 0; nt < 8; ++nt) {
        b2v[nt] = b2[nt * 16 + n_l];
        w3v[nt] = W3[nt * 16 + n_l];
    }

    f32x4 acc[4][8];
#pragma unroll
    for (int il = 0; il < 4; ++il)
#pragma unroll
        for (int nt = 0; nt < 8; ++nt) acc[il][nt] = f32x4{0.f, 0.f, 0.f, 0.f};

    const bf16x8* wbase = (const bf16x8*)w2f;
    bf16x8 wf[8], wfn[8];
#pragma unroll
    for (int nt = 0; nt < 8; ++nt) wf[nt] = wbase[(nt * 8 + 0) * 64 + l];

    __syncthreads();

#pragma unroll
    for (int ks = 0; ks < 8; ++ks) {
        if (ks < 7) {
#pragma unroll
            for (int nt = 0; nt < 8; ++nt) wfn[nt] = wbase[(nt * 8 + ks + 1) * 64 + l];
        }
#pragma unroll
        for (int il = 0; il < 4; ++il) {
            const int irow = w * 4 + il;
            bf16x8 ha = *(const bf16x8*)(&HaS[irow * 264 + ks * 32 + kq * 8]);
            bf16x8 hb = *(const bf16x8*)(&HbS[n_l * 264 + ks * 32 + kq * 8]);
            bf16x8 av;
#pragma unroll
            for (int e = 0; e < 8; ++e) {
                float v = bf2f((unsigned short)ha[e]) + bf2f((unsigned short)hb[e]);
                v = v > 0.f ? v : 0.f;
                av[e] = (short)f2bf(v);
            }
#pragma unroll
            for (int nt = 0; nt < 8; ++nt)
                acc[il][nt] = __builtin_amdgcn_mfma_f32_16x16x32_bf16(av, wf[nt], acc[il][nt], 0, 0, 0);
        }
#pragma unroll
        for (int nt = 0; nt < 8; ++nt) wf[nt] = wfn[nt];
    }

    const float bb3 = b3v[0];
#pragma unroll
    for (int il = 0; il < 4; ++il) {
        float p[4];
#pragma unroll
        for (int reg = 0; reg < 4; ++reg) {
            float v = 0.f;
#pragma unroll
            for (int nt = 0; nt < 8; ++nt) {
                float h2v = acc[il][nt][reg] + b2v[nt];
                h2v = h2v > 0.f ? h2v : 0.f;
                v += h2v * w3v[nt];
            }
            p[reg] = v;
        }
#pragma unroll
        for (int m = 1; m < 16; m <<= 1) {
            p[0] += __shfl_xor(p[0], m);
            p[1] += __shfl_xor(p[1], m);
            p[2] += __shfl_xor(p[2], m);
            p[3] += __shfl_xor(p[3], m);
        }
        if (n_l == 0) {
            const int i = i0 + w * 4 + il;
            const int jb = j0 + kq * 4;
            float4 sv;
            float* pv = &sv.x;
#pragma unroll
            for (int reg = 0; reg < 4; ++reg) {
                int jg = jb + reg;
                float sc = p[reg] + bb3;
                sc = sc > 0.f ? sc : 0.f;
                if (jg == i || jg == 0) sc = 0.f;
                pv[reg] = sc;
            }
            *(float4*)(&score[((size_t)(b * 128 + i)) * 128 + jb]) = sv;
        }
    }
}

// ---------------- loss ----------------
__global__ __launch_bounds__(128) void k_loss1(
    const float* __restrict__ score, const int* __restrict__ tree, float* __restrict__ res)
{
    int k = blockIdx.x;
    int b = blockIdx.y;
    int head = tree[((size_t)b * 128 + k + 1) * 2 + 0];
    int dep  = tree[((size_t)b * 128 + k + 1) * 2 + 1];
    int i = threadIdx.x;
    float s = score[((size_t)b * 128 + i) * 128 + dep];
    float v = (i == dep) ? 0.f : __expf(s);
    __shared__ float redu[2];
#pragma unroll
    for (int off = 32; off >= 1; off >>= 1) v += __shfl_down(v, off, 64);
    if ((i & 63) == 0) redu[i >> 6] = v;
    __syncthreads();
    if (i == 0) {
        float norm = redu[0] + redu[1];
        float num = score[((size_t)b * 128 + head) * 128 + dep];
        res[b * 127 + k] = __logf(norm) - num;
    }
}

__global__ __launch_bounds__(256) void k_loss2(const float* __restrict__ res, float* __restrict__ out) {
    int tid = threadIdx.x;
    float a = 0.f;
    for (int idx = tid; idx < 16 * 127; idx += 256) a += res[idx];
    __shared__ float sm[256];
    sm[tid] = a;
    __syncthreads();
    for (int off = 128; off >= 1; off >>= 1) {
        if (tid < off) sm[tid] += sm[tid + off];
        __syncthreads();
    }
    if (tid == 0) out[0] = sm[0] / 127.f;
}

// ---------------- host launcher ----------------
extern "C" void kernel_launch(void* const* d_in, const int* in_sizes, int n_in,
                              void* d_out, int out_size, void* d_ws, size_t ws_size,
                              hipStream_t stream) {
    (void)in_sizes; (void)n_in; (void)out_size; (void)ws_size;
    const float* X    = (const float*)d_in[0];
    const float* Wih0 = (const float*)d_in[1];
    const float* Whh0 = (const float*)d_in[2];
    const float* bih0 = (const float*)d_in[3];
    const float* bhh0 = (const float*)d_in[4];
    const float* Wih1 = (const float*)d_in[5];
    const float* Whh1 = (const float*)d_in[6];
    const float* bih1 = (const float*)d_in[7];
    const float* bhh1 = (const float*)d_in[8];
    const float* W1   = (const float*)d_in[9];
    const float* b1   = (const float*)d_in[10];
    const float* W2   = (const float*)d_in[11];
    const float* b2   = (const float*)d_in[12];
    const float* W3   = (const float*)d_in[13];
    const float* b3   = (const float*)d_in[14];
    const int*   tree = (const int*)d_in[15];
    float* out = (float*)d_out;   // [0]=loss, [1..]=score

    float* ws = (float*)d_ws;
    size_t o = 0;
    float* WihT0 = ws + o; o += (size_t)2 * 200 * 1024;
    float* WihT1 = ws + o; o += (size_t)2 * 512 * 1024;
    float* W1T   = ws + o; o += (size_t)512 * 512;
    float* bsum0 = ws + o; o += 2048;
    float* bsum1 = ws + o; o += 2048;
    float* bhab  = ws + o; o += 512;
    unsigned char* Wf0 = (unsigned char*)(ws + o); o += (size_t)2 * 16 * 8 * 4 * 64 * 8 / 4;
    unsigned char* Wf1 = (unsigned char*)(ws + o); o += (size_t)2 * 16 * 8 * 4 * 64 * 8 / 4;
    unsigned short* w2f = (unsigned short*)(ws + o); o += (size_t)8 * 8 * 64 * 8 / 2;
    float* xg   = ws + o; o += (size_t)2 * 2048 * 1024;
    float* xgf  = ws + o; o += (size_t)2 * 2048 * 1024;
    unsigned short* embt0 = (unsigned short*)(ws + o); o += (size_t)128 * 512 * 16 / 2;
    unsigned short* embt1 = (unsigned short*)(ws + o); o += (size_t)128 * 512 * 16 / 2;
    float* HaHb = ws + o; o += (size_t)2048 * 512;
    float* res  = ws + o; o += 2048;

    // prep
    k_transpose_N1024<<<dim3(800, 1, 2), 256, 0, stream>>>(Wih0, WihT0, 200);
    k_transpose_N1024<<<dim3(2048, 1, 2), 256, 0, stream>>>(Wih1, WihT1, 512);
    k_wfrag8<<<256, 256, 0, stream>>>(Whh0, Wf0);
    k_wfrag8<<<256, 256, 0, stream>>>(Whh1, Wf1);
    k_w2frag<<<16, 256, 0, stream>>>(W2, w2f);
    k_w1t<<<1024, 256, 0, stream>>>(W1, W1T);
    k_bias<<<18, 256, 0, stream>>>(bih0, bhh0, bih1, bhh1, b1, bsum0, bsum1, bhab);

    // layer 0
    k_gemm<<<dim3(4, 128, 2), 256, 0, stream>>>(X, WihT0, bsum0, xg, 2048, 200, 1024);
    k_reorder<<<4096, 256, 0, stream>>>(xg, xgf);
    k_lstm_mfma<<<2, 1024, 0, stream>>>(xgf, Wf0, embt0);
    // layer 1
    k_gemm_tl<<<dim3(4, 128, 2), 256, 0, stream>>>(embt0, WihT1, bsum1, xg, 512, 1024);
    k_reorder<<<4096, 256, 0, stream>>>(xg, xgf);
    k_lstm_mfma<<<2, 1024, 0, stream>>>(xgf, Wf1, embt1);
    // Ha|Hb
    k_gemm_tl<<<dim3(2, 128, 1), 256, 0, stream>>>(embt1, W1T, bhab, HaHb, 512, 512);
    // scorer -> out+1
    k_scorer_mfma<<<dim3(8, 8, 16), 256, 0, stream>>>(HaHb, w2f, b2, W3, b3, out + 1);
    // loss
    k_loss1<<<dim3(127, 16), 128, 0, stream>>>(out + 1, tree, res);
    k_loss2<<<1, 256, 0, stream>>>(res, out);
}

// Round 11
// 792.162 us; speedup vs baseline: 2.2753x; 1.3350x over previous
//
#include <hip/hip_runtime.h>
#include <hip/hip_bf16.h>
#include <cstdint>
#include <cstddef>

// B=16, S=128, IN=200, H=256, 4H=1024, 2H=512

typedef __attribute__((ext_vector_type(8))) short bf16x8;
typedef __attribute__((ext_vector_type(4))) float f32x4;
typedef __attribute__((ext_vector_type(4))) unsigned short u16x4;

__device__ __forceinline__ float bf2f(unsigned short u) {
    return __uint_as_float(((unsigned)u) << 16);
}
__device__ __forceinline__ unsigned short f2bf(float f) {
    unsigned u = __float_as_uint(f);
    u = (u + 0x7FFFu + ((u >> 16) & 1u)) >> 16;
    return (unsigned short)u;
}

// float -> OCP e4m3fn with RNE (software; used in prep only)
__device__ __forceinline__ unsigned f2e4m3(float f) {
    unsigned u = __float_as_uint(f);
    unsigned s = (u >> 24) & 0x80u;
    int expf_ = (int)((u >> 23) & 0xFF);
    if (expf_ == 0) return s;
    int exp = expf_ - 127;
    if (exp < -10) return s;
    unsigned M = (u & 0x7FFFFF) | 0x800000;
    int e8 = exp + 7;
    int shift = 20;
    if (e8 < 1) { shift = 21 - e8; e8 = 0; }
    unsigned q = M >> shift;
    unsigned rem = M & ((1u << shift) - 1u);
    unsigned half = 1u << (shift - 1);
    if (rem > half || (rem == half && (q & 1))) q++;
    if (q >= 16) { q >>= 1; e8++; }
    if (e8 == 0 && (q & 8)) e8 = 1;
    if (e8 >= 16 || (e8 == 15 && (q & 7) == 7)) return s | 0x7Eu;
    return s | ((unsigned)e8 << 4) | (q & 7u);
}

// ---------------- prep kernels ----------------

// dst[z][k][n] = src[z][n][k], n<1024, k<K
__global__ void k_transpose_N1024(const float* __restrict__ src, float* __restrict__ dst, int K) {
    int z = blockIdx.z;
    int idx = blockIdx.x * 256 + threadIdx.x;
    if (idx >= K * 1024) return;
    int k = idx >> 10, n = idx & 1023;
    dst[(size_t)z * K * 1024 + idx] = src[(size_t)z * 1024 * K + (size_t)n * K + k];
}

// Whh (2,1024,256) fp32 -> fp8(e4m3) A-fragment layout of 64*Whh, with the
// within-8 k-permutation cOf(e) = (e&1)*4 + (e>>1) applied (matches the hB
// pair-packed layout; MFMA contracts over k, so identical permutation on A
// and B is an identity).
__global__ void k_wfrag8(const float* __restrict__ Whh, unsigned char* __restrict__ Wfrag8) {
    int idx = blockIdx.x * 256 + threadIdx.x;   // 65536 total
    int l = idx & 63;
    int t = (idx >> 6) & 3;
    int ks = (idx >> 8) & 7;
    int w = (idx >> 11) & 15;
    int d = idx >> 15;
    int r = l & 15;
    int kbase = ks * 32 + (l >> 4) * 8;
    int row = (r & 3) * 256 + w * 16 + t * 4 + (r >> 2);
    const float* src = Whh + (size_t)d * (1024 * 256) + (size_t)row * 256 + kbase;
    unsigned char* dst = Wfrag8 + (size_t)idx * 8;
#pragma unroll
    for (int e = 0; e < 8; ++e) {
        int c = (e & 1) * 4 + (e >> 1);
        dst[e] = (unsigned char)f2e4m3(64.f * src[c]);
    }
}

// W2 (128,256) fp32 -> B-fragment layout bf16
__global__ void k_w2frag(const float* __restrict__ W2, unsigned short* __restrict__ w2f) {
    int idx = blockIdx.x * 256 + threadIdx.x;   // 4096 total
    if (idx >= 4096) return;
    int l = idx & 63;
    int ks = (idx >> 6) & 7;
    int nt = idx >> 9;
    const float* src = W2 + (size_t)(nt * 16 + (l & 15)) * 256 + ks * 32 + (l >> 4) * 8;
    unsigned short* dst = w2f + (size_t)idx * 8;
#pragma unroll
    for (int e = 0; e < 8; ++e) dst[e] = f2bf(src[e]);
}

// W1 (256,1024) -> dst[k][o], k<512, o<512
__global__ void k_w1t(const float* __restrict__ W1, float* __restrict__ dst) {
    int idx = blockIdx.x * 256 + threadIdx.x;
    if (idx >= 512 * 512) return;
    int k = idx >> 9, o = idx & 511;
    dst[idx] = (o < 256) ? W1[(size_t)o * 1024 + k] : W1[(size_t)(o - 256) * 1024 + 512 + k];
}

__global__ void k_bias(const float* __restrict__ bih0, const float* __restrict__ bhh0,
                       const float* __restrict__ bih1, const float* __restrict__ bhh1,
                       const float* __restrict__ b1,
                       float* __restrict__ bsum0, float* __restrict__ bsum1, float* __restrict__ bhab) {
    int idx = blockIdx.x * 256 + threadIdx.x;
    if (idx < 2048) bsum0[idx] = bih0[idx] + bhh0[idx];
    else if (idx < 4096) { int i = idx - 2048; bsum1[i] = bih1[i] + bhh1[i]; }
    else if (idx < 4608) { int i = idx - 4096; bhab[i] = (i < 256) ? b1[i] : 0.f; }
}

// xg[d][b*128+t][n] -> xgfrag, PRE-SCALED by 64 (fp8 weight-scale compensation)
__global__ __launch_bounds__(256) void k_reorder(const float* __restrict__ xg, float* __restrict__ xgf) {
    int idx = blockIdx.x * 256 + threadIdx.x;   // 1048576 total
    int n4 = idx & 255;
    int m = (idx >> 8) & 2047;
    int d = idx >> 19;
    int n0 = n4 * 4;
    int q = n0 >> 8;
    int jbase = n0 & 255;
    int b = m >> 7, t = m & 127;
    float4 v = *(const float4*)(xg + ((size_t)(d * 2048 + m)) * 1024 + n0);
    float* base = xgf + (size_t)d * 2097152;
    float vv[4] = {v.x * 64.f, v.y * 64.f, v.z * 64.f, v.w * 64.f};
#pragma unroll
    for (int dj = 0; dj < 4; ++dj) {
        int j = jbase + dj;
        int fi = (t * 4096 + (j >> 4) * 256 + ((j >> 2) & 3) * 64 + dj * 16 + b) * 4 + q;
        base[fi] = vv[dj];
    }
}

// ---------------- generic GEMM ----------------
__global__ __launch_bounds__(256) void k_gemm(
    const float* __restrict__ A, const float* __restrict__ Wt,
    const float* __restrict__ bias, float* __restrict__ out,
    int M, int K, int N)
{
    int z = blockIdx.z;
    const float* Wtz = Wt + (size_t)z * K * N;
    float* outz = out + (size_t)z * M * N;
    const float* biasz = bias + (size_t)z * N;

    __shared__ float As[16 * 512];
    int tid = threadIdx.x;
    int mq = tid >> 6;
    int nq = tid & 63;
    int n0 = blockIdx.x * 256 + nq * 4;
    int mbase = blockIdx.y * 16;

    for (int r = 0; r < 16; ++r) {
        const float* Ar = A + (size_t)(mbase + r) * K;
        for (int c = tid; c < K; c += 256) As[r * K + c] = Ar[c];
    }
    __syncthreads();

    float4 bv = *(const float4*)(biasz + n0);
    float acc[4][4];
#pragma unroll
    for (int mi = 0; mi < 4; mi++) { acc[mi][0] = bv.x; acc[mi][1] = bv.y; acc[mi][2] = bv.z; acc[mi][3] = bv.w; }

    const float* asr = As + (mq * 4) * K;
    for (int k = 0; k < K; ++k) {
        float4 w = *(const float4*)(Wtz + (size_t)k * N + n0);
        float x0 = asr[k];
        float x1 = asr[K + k];
        float x2 = asr[2 * K + k];
        float x3 = asr[3 * K + k];
        acc[0][0] += x0 * w.x; acc[0][1] += x0 * w.y; acc[0][2] += x0 * w.z; acc[0][3] += x0 * w.w;
        acc[1][0] += x1 * w.x; acc[1][1] += x1 * w.y; acc[1][2] += x1 * w.z; acc[1][3] += x1 * w.w;
        acc[2][0] += x2 * w.x; acc[2][1] += x2 * w.y; acc[2][2] += x2 * w.z; acc[2][3] += x2 * w.w;
        acc[3][0] += x3 * w.x; acc[3][1] += x3 * w.y; acc[3][2] += x3 * w.z; acc[3][3] += x3 * w.w;
    }
#pragma unroll
    for (int mi = 0; mi < 4; mi++) {
        size_t m = (size_t)mbase + mq * 4 + mi;
        *(float4*)(outz + m * N + n0) = make_float4(acc[mi][0], acc[mi][1], acc[mi][2], acc[mi][3]);
    }
}

// Same GEMM but A is bf16 in [t][j][b] layout
__global__ __launch_bounds__(256) void k_gemm_tl(
    const unsigned short* __restrict__ embt, const float* __restrict__ Wt,
    const float* __restrict__ bias, float* __restrict__ out,
    int K, int N)
{
    int z = blockIdx.z;
    const float* Wtz = Wt + (size_t)z * K * N;
    float* outz = out + (size_t)z * 2048 * N;
    const float* biasz = bias + (size_t)z * N;

    __shared__ float As[16 * 512];
    int tid = threadIdx.x;
    int mq = tid >> 6;
    int nq = tid & 63;
    int n0 = blockIdx.x * 256 + nq * 4;
    int mbase = blockIdx.y * 16;
    int bb = mbase >> 7;
    int tt0 = mbase & 127;

    for (int r = 0; r < 16; ++r) {
        const unsigned short* Ar = embt + (size_t)(tt0 + r) * 8192 + bb;
        for (int c = tid; c < K; c += 256) As[r * K + c] = bf2f(Ar[c * 16]);
    }
    __syncthreads();

    float4 bv = *(const float4*)(biasz + n0);
    float acc[4][4];
#pragma unroll
    for (int mi = 0; mi < 4; mi++) { acc[mi][0] = bv.x; acc[mi][1] = bv.y; acc[mi][2] = bv.z; acc[mi][3] = bv.w; }

    const float* asr = As + (mq * 4) * K;
    for (int k = 0; k < K; ++k) {
        float4 w = *(const float4*)(Wtz + (size_t)k * N + n0);
        float x0 = asr[k];
        float x1 = asr[K + k];
        float x2 = asr[2 * K + k];
        float x3 = asr[3 * K + k];
        acc[0][0] += x0 * w.x; acc[0][1] += x0 * w.y; acc[0][2] += x0 * w.z; acc[0][3] += x0 * w.w;
        acc[1][0] += x1 * w.x; acc[1][1] += x1 * w.y; acc[1][2] += x1 * w.z; acc[1][3] += x1 * w.w;
        acc[2][0] += x2 * w.x; acc[2][1] += x2 * w.y; acc[2][2] += x2 * w.z; acc[2][3] += x2 * w.w;
        acc[3][0] += x3 * w.x; acc[3][1] += x3 * w.y; acc[3][2] += x3 * w.z; acc[3][3] += x3 * w.w;
    }
#pragma unroll
    for (int mi = 0; mi < 4; mi++) {
        size_t m = (size_t)mbase + mq * 4 + mi;
        *(float4*)(outz + m * N + n0) = make_float4(acc[mi][0], acc[mi][1], acc[mi][2], acc[mi][3]);
    }
}

// ---------------- MFMA LSTM recurrence: 512 threads, 2 slots/wave ----------
// 8 waves * 2 slots; fp8 weights for both slots = 128 VGPRs, budget 256
// (launch_bounds 512,2). HW cvt_pk for fp8 h-state and bf16 emb. hB layout:
// byte = (k>>3)*128 + b*8 + p, p = (k&3)*2 + (k>>2 within 8) -- pairs of a
// thread's h values are adjacent -> u16 writes; k-perm matched in k_wfrag8.
#define GATE8(A, C, H) { \
    float gi = A[0] * 0.015625f, gf = A[1] * 0.015625f, gg = A[2] * 0.015625f, go = A[3] * 0.015625f; \
    float si = __builtin_amdgcn_rcpf(1.f + __expf(-gi)); \
    float sf = __builtin_amdgcn_rcpf(1.f + __expf(-gf)); \
    float so = __builtin_amdgcn_rcpf(1.f + __expf(-go)); \
    float eg = __expf(2.f * gg); \
    float tg = 1.f - 2.f * __builtin_amdgcn_rcpf(eg + 1.f); \
    C = sf * C + si * tg; \
    float ec = __expf(2.f * C); \
    float tc = 1.f - 2.f * __builtin_amdgcn_rcpf(ec + 1.f); \
    H = so * tc; }

__global__ __launch_bounds__(512, 2) void k_lstm_mfma(
    const float* __restrict__ xgf,            // [2][128][16][4][64][4], pre-scaled x64
    const unsigned char* __restrict__ Wfrag8, // [2][16][8][4][64][8] fp8 of 64*Whh (k-perm)
    unsigned short* __restrict__ embt)        // [128][512][16] bf16 ([t][j][b])
{
    const int d = blockIdx.x;
    const int tid = threadIdx.x;
    const int wv = tid >> 6;      // 0..7
    const int l = tid & 63;
    const int b = l & 15;
    const int jh = l >> 4;
    const int s0 = wv * 2, s1 = wv * 2 + 1;

    __shared__ __align__(8) unsigned char hB[4096];   // fp8 h, single buffer

    // 2 slots of fp8 weights per wave: 64 longs = 128 VGPRs, pinned
    const unsigned char* wg0 = Wfrag8 + ((size_t)(d * 16 + s0)) * 16384;
    const unsigned char* wg1 = Wfrag8 + ((size_t)(d * 16 + s1)) * 16384;
    long W0[8][4], W1[8][4];
#pragma unroll
    for (int ks = 0; ks < 8; ++ks)
#pragma unroll
        for (int t4 = 0; t4 < 4; ++t4) {
            W0[ks][t4] = *(const long*)(wg0 + ((size_t)((ks * 4 + t4) * 64 + l)) * 8);
            W1[ks][t4] = *(const long*)(wg1 + ((size_t)((ks * 4 + t4) * 64 + l)) * 8);
        }
#pragma unroll
    for (int ks = 0; ks < 8; ++ks)
#pragma unroll
        for (int t4 = 0; t4 < 4; ++t4) {
            asm volatile("" : "+v"(W0[ks][t4]));
            asm volatile("" : "+v"(W1[ks][t4]));
        }

    ((uint64_t*)hB)[tid] = 0ull;   // 512*8 = 4096

    const int sgn = d ? -1 : 1;
    int t = d ? 127 : 0;
    const f32x4* xb = (const f32x4*)(xgf) + (size_t)d * 524288;
    const int xo0 = s0 * 256 + l;
    const int xo1 = s1 * 256 + l;

    f32x4 a0 = xb[t * 4096 + xo0];
    f32x4 a1 = xb[t * 4096 + xo0 + 64];
    f32x4 a2 = xb[t * 4096 + xo0 + 128];
    f32x4 a3 = xb[t * 4096 + xo0 + 192];
    f32x4 e0 = xb[t * 4096 + xo1];
    f32x4 e1 = xb[t * 4096 + xo1 + 64];
    f32x4 e2 = xb[t * 4096 + xo1 + 128];
    f32x4 e3 = xb[t * 4096 + xo1 + 192];

    float c0 = 0.f, c1 = 0.f, c2 = 0.f, c3 = 0.f;
    float c4 = 0.f, c5 = 0.f, c6 = 0.f, c7 = 0.f;
    const int hrd = jh * 128 + b * 8;                    // + ks*512 (bytes)
    unsigned short* ep0 = embt + (size_t)d * 4096 + (size_t)s0 * 256 + l;
    unsigned short* ep1 = embt + (size_t)d * 4096 + (size_t)s1 * 256 + l;
    unsigned char* hw0 = hB + s0 * 256 + b * 8 + jh * 2; // +0: t4=0,1 ; +128: t4=2,3
    unsigned char* hw1 = hB + s1 * 256 + b * 8 + jh * 2;
    __syncthreads();

    for (int s = 0; s < 128; ++s) {
#pragma unroll
        for (int ks = 0; ks < 8; ++ks) {
            long hf = *(const long*)(hB + ks * 512 + hrd);
            a0 = __builtin_amdgcn_mfma_f32_16x16x32_fp8_fp8(W0[ks][0], hf, a0, 0, 0, 0);
            a1 = __builtin_amdgcn_mfma_f32_16x16x32_fp8_fp8(W0[ks][1], hf, a1, 0, 0, 0);
            a2 = __builtin_amdgcn_mfma_f32_16x16x32_fp8_fp8(W0[ks][2], hf, a2, 0, 0, 0);
            a3 = __builtin_amdgcn_mfma_f32_16x16x32_fp8_fp8(W0[ks][3], hf, a3, 0, 0, 0);
            e0 = __builtin_amdgcn_mfma_f32_16x16x32_fp8_fp8(W1[ks][0], hf, e0, 0, 0, 0);
            e1 = __builtin_amdgcn_mfma_f32_16x16x32_fp8_fp8(W1[ks][1], hf, e1, 0, 0, 0);
            e2 = __builtin_amdgcn_mfma_f32_16x16x32_fp8_fp8(W1[ks][2], hf, e2, 0, 0, 0);
            e3 = __builtin_amdgcn_mfma_f32_16x16x32_fp8_fp8(W1[ks][3], hf, e3, 0, 0, 0);
        }

        float h0, h1, h2, h3, h4, h5, h6, h7;
        GATE8(a0, c0, h0);
        GATE8(a1, c1, h1);
        GATE8(a2, c2, h2);
        GATE8(a3, c3, h3);
        GATE8(e0, c4, h4);
        GATE8(e1, c5, h5);
        GATE8(e2, c6, h6);
        GATE8(e3, c7, h7);

        // emb bf16 via HW packed cvt (2 f32 -> 2 bf16 per instr)
        unsigned r01, r23, r45, r67;
        asm("v_cvt_pk_bf16_f32 %0, %1, %2" : "=v"(r01) : "v"(h0), "v"(h1));
        asm("v_cvt_pk_bf16_f32 %0, %1, %2" : "=v"(r23) : "v"(h2), "v"(h3));
        asm("v_cvt_pk_bf16_f32 %0, %1, %2" : "=v"(r45) : "v"(h4), "v"(h5));
        asm("v_cvt_pk_bf16_f32 %0, %1, %2" : "=v"(r67) : "v"(h6), "v"(h7));
        {
            unsigned short* p0 = ep0 + (size_t)t * 8192;
            p0[0]   = (unsigned short)r01;
            p0[64]  = (unsigned short)(r01 >> 16);
            p0[128] = (unsigned short)r23;
            p0[192] = (unsigned short)(r23 >> 16);
            unsigned short* p1 = ep1 + (size_t)t * 8192;
            p1[0]   = (unsigned short)r45;
            p1[64]  = (unsigned short)(r45 >> 16);
            p1[128] = (unsigned short)r67;
            p1[192] = (unsigned short)(r67 >> 16);
        }

        // fp8 h pairs via HW packed cvt (byte0 = first arg, byte1 = second)
        unsigned q01 = __builtin_amdgcn_cvt_pk_fp8_f32(h0, h1, 0, false);
        unsigned q23 = __builtin_amdgcn_cvt_pk_fp8_f32(h2, h3, 0, false);
        unsigned q45 = __builtin_amdgcn_cvt_pk_fp8_f32(h4, h5, 0, false);
        unsigned q67 = __builtin_amdgcn_cvt_pk_fp8_f32(h6, h7, 0, false);

        // prefetch next step's xg into acc (drained by the barrier)
        int tn = (s == 127) ? t : (t + sgn);
        a0 = xb[tn * 4096 + xo0];
        a1 = xb[tn * 4096 + xo0 + 64];
        a2 = xb[tn * 4096 + xo0 + 128];
        a3 = xb[tn * 4096 + xo0 + 192];
        e0 = xb[tn * 4096 + xo1];
        e1 = xb[tn * 4096 + xo1 + 64];
        e2 = xb[tn * 4096 + xo1 + 128];
        e3 = xb[tn * 4096 + xo1 + 192];
        __syncthreads();   // all reads of h_{s-1} complete
        *(unsigned short*)(hw0)       = (unsigned short)q01;
        *(unsigned short*)(hw0 + 128) = (unsigned short)q23;
        *(unsigned short*)(hw1)       = (unsigned short)q45;
        *(unsigned short*)(hw1 + 128) = (unsigned short)q67;
        __syncthreads();   // h_s visible
        t = tn;
    }
}

// ---------------- MFMA pairwise scorer (R7 winner, unchanged) ----------------
__global__ __launch_bounds__(256, 2) void k_scorer_mfma(
    const float* __restrict__ HaHb, const unsigned short* __restrict__ w2f,
    const float* __restrict__ b2, const float* __restrict__ W3,
    const float* __restrict__ b3v, float* __restrict__ score)
{
    const int jt = blockIdx.x, it = blockIdx.y, b = blockIdx.z;
    const int j0 = jt * 16, i0 = it * 16;
    const int tid = threadIdx.x;
    const int w = tid >> 6;
    const int l = tid & 63;
    const int n_l = l & 15;
    const int kq = l >> 4;

    __shared__ __align__(16) unsigned short HaS[16 * 264];
    __shared__ __align__(16) unsigned short HbS[16 * 264];

    {
        const float* base = HaHb + ((size_t)(b * 128)) * 512;
        int rr = tid >> 4;
        int q = tid & 15;
#pragma unroll
        for (int rep = 0; rep < 4; ++rep) {
            int k0 = q * 4 + rep * 64;
            float4 va = *(const float4*)(base + (size_t)(i0 + rr) * 512 + k0);
            float4 vb = *(const float4*)(base + (size_t)(j0 + rr) * 512 + 256 + k0);
            u16x4 ua = { f2bf(va.x), f2bf(va.y), f2bf(va.z), f2bf(va.w) };
            u16x4 ub = { f2bf(vb.x), f2bf(vb.y), f2bf(vb.z), f2bf(vb.w) };
            *(u16x4*)(&HaS[rr * 264 + k0]) = ua;
            *(u16x4*)(&HbS[rr * 264 + k0]) = ub;
        }
    }

    float b2v[8], w3v[8];
#pragma unroll
    for (int nt = 0; nt < 8; ++nt) {
        b2v[nt] = b2[nt * 16 + n_l];
        w3v[nt] = W3[nt * 16 + n_l];
    }

    f32x4 acc[4][8];
#pragma unroll
    for (int il = 0; il < 4; ++il)
#pragma unroll
        for (int nt = 0; nt < 8; ++nt) acc[il][nt] = f32x4{0.f, 0.f, 0.f, 0.f};

    const bf16x8* wbase = (const bf16x8*)w2f;
    bf16x8 wf[8], wfn[8];
#pragma unroll
    for (int nt = 0; nt < 8; ++nt) wf[nt] = wbase[(nt * 8 + 0) * 64 + l];

    __syncthreads();

#pragma unroll
    for (int ks = 0; ks < 8; ++ks) {
        if (ks < 7) {
#pragma unroll
            for (int nt = 0; nt < 8; ++nt) wfn[nt] = wbase[(nt * 8 + ks + 1) * 64 + l];
        }
#pragma unroll
        for (int il = 0; il < 4; ++il) {
            const int irow = w * 4 + il;
            bf16x8 ha = *(const bf16x8*)(&HaS[irow * 264 + ks * 32 + kq * 8]);
            bf16x8 hb = *(const bf16x8*)(&HbS[n_l * 264 + ks * 32 + kq * 8]);
            bf16x8 av;
#pragma unroll
            for (int e = 0; e < 8; ++e) {
                float v = bf2f((unsigned short)ha[e]) + bf2f((unsigned short)hb[e]);
                v = v > 0.f ? v : 0.f;
                av[e] = (short)f2bf(v);
            }
#pragma unroll
            for (int nt = 0; nt < 8; ++nt)
                acc[il][nt] = __builtin_amdgcn_mfma_f32_16x16x32_bf16(av, wf[nt], acc[il][nt], 0, 0, 0);
        }
#pragma unroll
        for (int nt = 0; nt < 8; ++nt) wf[nt] = wfn[nt];
    }

    const float bb3 = b3v[0];
#pragma unroll
    for (int il = 0; il < 4; ++il) {
        float p[4];
#pragma unroll
        for (int reg = 0; reg < 4; ++reg) {
            float v = 0.f;
#pragma unroll
            for (int nt = 0; nt < 8; ++nt) {
                float h2v = acc[il][nt][reg] + b2v[nt];
                h2v = h2v > 0.f ? h2v : 0.f;
                v += h2v * w3v[nt];
            }
            p[reg] = v;
        }
#pragma unroll
        for (int m = 1; m < 16; m <<= 1) {
            p[0] += __shfl_xor(p[0], m);
            p[1] += __shfl_xor(p[1], m);
            p[2] += __shfl_xor(p[2], m);
            p[3] += __shfl_xor(p[3], m);
        }
        if (n_l == 0) {
            const int i = i0 + w * 4 + il;
            const int jb = j0 + kq * 4;
            float4 sv;
            float* pv = &sv.x;
#pragma unroll
            for (int reg = 0; reg < 4; ++reg) {
                int jg = jb + reg;
                float sc = p[reg] + bb3;
                sc = sc > 0.f ? sc : 0.f;
                if (jg == i || jg == 0) sc = 0.f;
                pv[reg] = sc;
            }
            *(float4*)(&score[((size_t)(b * 128 + i)) * 128 + jb]) = sv;
        }
    }
}

// ---------------- loss ----------------
__global__ __launch_bounds__(128) void k_loss1(
    const float* __restrict__ score, const int* __restrict__ tree, float* __restrict__ res)
{
    int k = blockIdx.x;
    int b = blockIdx.y;
    int head = tree[((size_t)b * 128 + k + 1) * 2 + 0];
    int dep  = tree[((size_t)b * 128 + k + 1) * 2 + 1];
    int i = threadIdx.x;
    float s = score[((size_t)b * 128 + i) * 128 + dep];
    float v = (i == dep) ? 0.f : __expf(s);
    __shared__ float redu[2];
#pragma unroll
    for (int off = 32; off >= 1; off >>= 1) v += __shfl_down(v, off, 64);
    if ((i & 63) == 0) redu[i >> 6] = v;
    __syncthreads();
    if (i == 0) {
        float norm = redu[0] + redu[1];
        float num = score[((size_t)b * 128 + head) * 128 + dep];
        res[b * 127 + k] = __logf(norm) - num;
    }
}

__global__ __launch_bounds__(256) void k_loss2(const float* __restrict__ res, float* __restrict__ out) {
    int tid = threadIdx.x;
    float a = 0.f;
    for (int idx = tid; idx < 16 * 127; idx += 256) a += res[idx];
    __shared__ float sm[256];
    sm[tid] = a;
    __syncthreads();
    for (int off = 128; off >= 1; off >>= 1) {
        if (tid < off) sm[tid] += sm[tid + off];
        __syncthreads();
    }
    if (tid == 0) out[0] = sm[0] / 127.f;
}

// ---------------- host launcher ----------------
extern "C" void kernel_launch(void* const* d_in, const int* in_sizes, int n_in,
                              void* d_out, int out_size, void* d_ws, size_t ws_size,
                              hipStream_t stream) {
    (void)in_sizes; (void)n_in; (void)out_size; (void)ws_size;
    const float* X    = (const float*)d_in[0];
    const float* Wih0 = (const float*)d_in[1];
    const float* Whh0 = (const float*)d_in[2];
    const float* bih0 = (const float*)d_in[3];
    const float* bhh0 = (const float*)d_in[4];
    const float* Wih1 = (const float*)d_in[5];
    const float* Whh1 = (const float*)d_in[6];
    const float* bih1 = (const float*)d_in[7];
    const float* bhh1 = (const float*)d_in[8];
    const float* W1   = (const float*)d_in[9];
    const float* b1   = (const float*)d_in[10];
    const float* W2   = (const float*)d_in[11];
    const float* b2   = (const float*)d_in[12];
    const float* W3   = (const float*)d_in[13];
    const float* b3   = (const float*)d_in[14];
    const int*   tree = (const int*)d_in[15];
    float* out = (float*)d_out;   // [0]=loss, [1..]=score

    float* ws = (float*)d_ws;
    size_t o = 0;
    float* WihT0 = ws + o; o += (size_t)2 * 200 * 1024;
    float* WihT1 = ws + o; o += (size_t)2 * 512 * 1024;
    float* W1T   = ws + o; o += (size_t)512 * 512;
    float* bsum0 = ws + o; o += 2048;
    float* bsum1 = ws + o; o += 2048;
    float* bhab  = ws + o; o += 512;
    unsigned char* Wf0 = (unsigned char*)(ws + o); o += (size_t)2 * 16 * 8 * 4 * 64 * 8 / 4;
    unsigned char* Wf1 = (unsigned char*)(ws + o); o += (size_t)2 * 16 * 8 * 4 * 64 * 8 / 4;
    unsigned short* w2f = (unsigned short*)(ws + o); o += (size_t)8 * 8 * 64 * 8 / 2;
    float* xg   = ws + o; o += (size_t)2 * 2048 * 1024;
    float* xgf  = ws + o; o += (size_t)2 * 2048 * 1024;
    unsigned short* embt0 = (unsigned short*)(ws + o); o += (size_t)128 * 512 * 16 / 2;
    unsigned short* embt1 = (unsigned short*)(ws + o); o += (size_t)128 * 512 * 16 / 2;
    float* HaHb = ws + o; o += (size_t)2048 * 512;
    float* res  = ws + o; o += 2048;

    // prep
    k_transpose_N1024<<<dim3(800, 1, 2), 256, 0, stream>>>(Wih0, WihT0, 200);
    k_transpose_N1024<<<dim3(2048, 1, 2), 256, 0, stream>>>(Wih1, WihT1, 512);
    k_wfrag8<<<256, 256, 0, stream>>>(Whh0, Wf0);
    k_wfrag8<<<256, 256, 0, stream>>>(Whh1, Wf1);
    k_w2frag<<<16, 256, 0, stream>>>(W2, w2f);
    k_w1t<<<1024, 256, 0, stream>>>(W1, W1T);
    k_bias<<<18, 256, 0, stream>>>(bih0, bhh0, bih1, bhh1, b1, bsum0, bsum1, bhab);

    // layer 0
    k_gemm<<<dim3(4, 128, 2), 256, 0, stream>>>(X, WihT0, bsum0, xg, 2048, 200, 1024);
    k_reorder<<<4096, 256, 0, stream>>>(xg, xgf);
    k_lstm_mfma<<<2, 512, 0, stream>>>(xgf, Wf0, embt0);
    // layer 1
    k_gemm_tl<<<dim3(4, 128, 2), 256, 0, stream>>>(embt0, WihT1, bsum1, xg, 512, 1024);
    k_reorder<<<4096, 256, 0, stream>>>(xg, xgf);
    k_lstm_mfma<<<2, 512, 0, stream>>>(xgf, Wf1, embt1);
    // Ha|Hb
    k_gemm_tl<<<dim3(2, 128, 1), 256, 0, stream>>>(embt1, W1T, bhab, HaHb, 512, 512);
    // scorer -> out+1
    k_scorer_mfma<<<dim3(8, 8, 16), 256, 0, stream>>>(HaHb, w2f, b2, W3, b3, out + 1);
    // loss
    k_loss1<<<dim3(127, 16), 128, 0, stream>>>(out + 1, tree, res);
    k_loss2<<<1, 256, 0, stream>>>(res, out);
}